// Round 2
// baseline (443.098 us; speedup 1.0000x reference)
//
#include <hip/hip_runtime.h>

#define DIM 32
#define BLOCK 256
#define RS 36     // padded LDS row stride in floats: conflict-free at 16-lane phase granularity
#define TILES 4   // 64-row tiles per wave; grid = B/(BLOCK*TILES) = 1024 = exactly 4 blocks/CU

// d_ws layout: c[32][32] folded coefficients, then s[32], then m[32]  (1088 floats)
//   c[i][j] = -P[i][j]/P[i][i]  (j != i),  c[i][i] = 0
//   s[i]    = sqrt(1/P[i][i])
//   m[i]    = mu[i]
__global__ __launch_bounds__(256) void gibbs_setup_kernel(
    const float* __restrict__ prec,
    const float* __restrict__ mu,
    float* __restrict__ ws)
{
    const int t = threadIdx.x;
#pragma unroll
    for (int k = 0; k < 4; ++k) {
        const int idx = t * 4 + k;
        const int i = idx >> 5;
        const int j = idx & 31;
        const float pii = prec[i * DIM + i];
        ws[idx] = (j == i) ? 0.0f : (-prec[idx] / pii);
    }
    if (t < DIM) {
        const float pii = prec[t * DIM + t];
        ws[1024 + t] = sqrtf(1.0f / pii);
        ws[1056 + t] = mu[t];
    }
}

// Same association as the passing kernel: 4 chains of 8 FMAs.
#define G8(C, X, o) \
    ((C)[(o)+0]*(X)[(o)+0] + (C)[(o)+1]*(X)[(o)+1] + (C)[(o)+2]*(X)[(o)+2] + (C)[(o)+3]*(X)[(o)+3] \
   + (C)[(o)+4]*(X)[(o)+4] + (C)[(o)+5]*(X)[(o)+5] + (C)[(o)+6]*(X)[(o)+6] + (C)[(o)+7]*(X)[(o)+7])

// One thread = one row; all global I/O wave-coalesced through a padded per-wave
// LDS chunk (no cross-wave sharing -> no barriers; DS ops complete in order
// within a wave, so chunk reuse x -> noise -> out needs no explicit waits).
// Each wave pipelines TILES tiles: next tile's 16 global loads are issued
// before this tile's compute so HBM streams under the ~2600-cycle sweep.
__global__ __launch_bounds__(BLOCK, 4) void gibbs_sweep_kernel(
    const float* __restrict__ x,
    const float* __restrict__ noise,
    const float* __restrict__ ws,
    float* __restrict__ out)
{
    __shared__ float lds[4][64 * RS];   // 4 waves * 9216 B = 36 KB/block

    const float* __restrict__ cw = ws;          // 32x32 folded coefficients
    const float* __restrict__ sw = ws + 1024;   // sqrt(1/Pii)
    const float* __restrict__ mw = ws + 1056;   // mu

    const int wid  = threadIdx.x >> 6;
    const int lane = threadIdx.x & 63;
    const long w = (long)blockIdx.x * 4 + wid;  // global wave id

    const float4* __restrict__ x4 = (const float4*)x;
    const float4* __restrict__ n4 = (const float4*)noise;
    float4* __restrict__ o4 = (float4*)out;

    float* L = lds[wid];

    // Prologue: tile 0 loads (coalesced: lane l -> float4 k*64+l, 1 KB/instr).
    float4 vx[8], vn[8];
    {
        const long b0 = w * (long)TILES * 512;  // 512 float4 per 64x32 tile
#pragma unroll
        for (int k = 0; k < 8; ++k) vx[k] = x4[b0 + k * 64 + lane];
#pragma unroll
        for (int k = 0; k < 8; ++k) vn[k] = n4[b0 + k * 64 + lane];
    }

#pragma unroll 1
    for (int t = 0; t < TILES; ++t) {
        const long bcur  = (w * TILES + t) * 512L;
        const long bnext = bcur + ((t + 1 < TILES) ? 512L : 0L);  // clamp: harmless re-read on last

        float xv[32];

        // ---- x: regs -> padded LDS ----
#pragma unroll
        for (int k = 0; k < 8; ++k) {
            const int f = k * 64 + lane;
            *(float4*)(L + (f >> 3) * RS + (f & 7) * 4) = vx[k];
        }
        // vx consumed -> issue next tile's x loads now (in flight through compute)
#pragma unroll
        for (int k = 0; k < 8; ++k) vx[k] = x4[bnext + k * 64 + lane];
        __builtin_amdgcn_sched_barrier(0);   // don't let the scheduler sink these loads

        // ---- x rows -> registers ----
#pragma unroll
        for (int c = 0; c < 8; ++c) {
            const float4 v = *(const float4*)(L + lane * RS + c * 4);
            xv[c * 4 + 0] = v.x; xv[c * 4 + 1] = v.y;
            xv[c * 4 + 2] = v.z; xv[c * 4 + 3] = v.w;
        }

        // ---- noise: regs -> padded LDS (stays there; read lazily in the sweep) ----
#pragma unroll
        for (int k = 0; k < 8; ++k) {
            const int f = k * 64 + lane;
            *(float4*)(L + (f >> 3) * RS + (f & 7) * 4) = vn[k];
        }
#pragma unroll
        for (int k = 0; k < 8; ++k) vn[k] = n4[bnext + k * 64 + lane];
        __builtin_amdgcn_sched_barrier(0);

        // ---- sequential Gibbs sweep; noise quad pulled from LDS every 4 steps ----
        // (keeps VGPR <=128 for 4 waves/SIMD; numeric grouping identical to passing kernel)
        float4 nq;
#pragma unroll
        for (int i = 0; i < 32; ++i) {
            if ((i & 3) == 0) nq = *(const float4*)(L + lane * RS + i);
            const float ni = (i & 3) == 0 ? nq.x : (i & 3) == 1 ? nq.y : (i & 3) == 2 ? nq.z : nq.w;
            const float* __restrict__ ci = cw + i * DIM;
            const float d = ((G8(ci, xv, 0) + G8(ci, xv, 8))
                           + (G8(ci, xv, 16) + G8(ci, xv, 24)));
            xv[i] = fmaf(sw[i], ni, mw[i] + d);
        }

        // ---- out: rows -> padded LDS -> coalesced global stores ----
#pragma unroll
        for (int c = 0; c < 8; ++c) {
            *(float4*)(L + lane * RS + c * 4) =
                make_float4(xv[c * 4 + 0], xv[c * 4 + 1], xv[c * 4 + 2], xv[c * 4 + 3]);
        }
#pragma unroll
        for (int k = 0; k < 8; ++k) {
            const int f = k * 64 + lane;
            o4[bcur + f] = *(const float4*)(L + (f >> 3) * RS + (f & 7) * 4);
        }
    }
}

extern "C" void kernel_launch(void* const* d_in, const int* in_sizes, int n_in,
                              void* d_out, int out_size, void* d_ws, size_t ws_size,
                              hipStream_t stream) {
    const float* x     = (const float*)d_in[0];  // (B, 32)
    const float* noise = (const float*)d_in[1];  // (B, 32)
    const float* prec  = (const float*)d_in[2];  // (32, 32)
    const float* mu    = (const float*)d_in[3];  // (32,)
    float* out = (float*)d_out;
    float* ws  = (float*)d_ws;                   // needs 1088 floats (4.25 KB)

    const int B = in_sizes[0] / DIM;             // 1048576
    const int grid = B / (BLOCK * TILES);        // 1024 blocks = 4 blocks/CU, all resident

    gibbs_setup_kernel<<<1, 256, 0, stream>>>(prec, mu, ws);
    gibbs_sweep_kernel<<<grid, BLOCK, 0, stream>>>(x, noise, ws, out);
}

// Round 4
// 405.921 us; speedup vs baseline: 1.0916x; 1.0916x over previous
//
#include <hip/hip_runtime.h>

#define DIM 32
#define BLOCK 256
#define RS 36     // padded LDS row stride in floats: conflict-free at 16-lane phase granularity
#define TILES 2   // 64-row tiles per wave; grid = B/(BLOCK*TILES) = 2048
                  // resident footprint = 4 blk/CU * 256 CU * 192 KB = 196 MB < 256 MB LLC

typedef float vfloat4 __attribute__((ext_vector_type(4)));  // native vec for nontemporal builtin

// d_ws layout: c[32][32] folded coefficients, then s[32], then m[32]  (1088 floats)
//   c[i][j] = -P[i][j]/P[i][i]  (j != i),  c[i][i] = 0
//   s[i]    = sqrt(1/P[i][i])
//   m[i]    = mu[i]
__global__ __launch_bounds__(256) void gibbs_setup_kernel(
    const float* __restrict__ prec,
    const float* __restrict__ mu,
    float* __restrict__ ws)
{
    const int t = threadIdx.x;
#pragma unroll
    for (int k = 0; k < 4; ++k) {
        const int idx = t * 4 + k;
        const int i = idx >> 5;
        const int j = idx & 31;
        const float pii = prec[i * DIM + i];
        ws[idx] = (j == i) ? 0.0f : (-prec[idx] / pii);
    }
    if (t < DIM) {
        const float pii = prec[t * DIM + t];
        ws[1024 + t] = sqrtf(1.0f / pii);
        ws[1056 + t] = mu[t];
    }
}

// Same association as the passing kernel: 4 chains of 8 FMAs.
#define G8(C, X, o) \
    ((C)[(o)+0]*(X)[(o)+0] + (C)[(o)+1]*(X)[(o)+1] + (C)[(o)+2]*(X)[(o)+2] + (C)[(o)+3]*(X)[(o)+3] \
   + (C)[(o)+4]*(X)[(o)+4] + (C)[(o)+5]*(X)[(o)+5] + (C)[(o)+6]*(X)[(o)+6] + (C)[(o)+7]*(X)[(o)+7])

// One 64-row tile: stage x/noise regs->LDS, pull rows to registers, run the
// sequential sweep (noise quads lazily from LDS), write out via LDS with
// nontemporal stores. If PREFETCH, issue next tile's 16 global loads as soon
// as the current register copies are consumed (in flight through the sweep).
template<bool PREFETCH>
__device__ __forceinline__ void gibbs_tile(
    float* __restrict__ L,
    const float* __restrict__ cw, const float* __restrict__ sw, const float* __restrict__ mw,
    const float4* __restrict__ x4, const float4* __restrict__ n4, float4* __restrict__ o4,
    long bcur, long bnext, int lane, float4 vx[8], float4 vn[8])
{
    float xv[32];

    // ---- x: regs -> padded LDS ----
#pragma unroll
    for (int k = 0; k < 8; ++k) {
        const int f = k * 64 + lane;
        *(float4*)(L + (f >> 3) * RS + (f & 7) * 4) = vx[k];
    }
    if (PREFETCH) {   // vx consumed -> refill with next tile's x (coalesced 1 KB/instr)
#pragma unroll
        for (int k = 0; k < 8; ++k) vx[k] = x4[bnext + k * 64 + lane];
        __builtin_amdgcn_sched_barrier(0);   // keep these loads up here
    }

    // ---- x rows -> registers ----
#pragma unroll
    for (int c = 0; c < 8; ++c) {
        const float4 v = *(const float4*)(L + lane * RS + c * 4);
        xv[c * 4 + 0] = v.x; xv[c * 4 + 1] = v.y;
        xv[c * 4 + 2] = v.z; xv[c * 4 + 3] = v.w;
    }

    // ---- noise: regs -> padded LDS (read lazily during the sweep) ----
#pragma unroll
    for (int k = 0; k < 8; ++k) {
        const int f = k * 64 + lane;
        *(float4*)(L + (f >> 3) * RS + (f & 7) * 4) = vn[k];
    }
    if (PREFETCH) {
#pragma unroll
        for (int k = 0; k < 8; ++k) vn[k] = n4[bnext + k * 64 + lane];
        __builtin_amdgcn_sched_barrier(0);
    }

    // ---- sequential Gibbs sweep; numeric grouping identical to passing kernel ----
    float4 nq;
#pragma unroll
    for (int i = 0; i < 32; ++i) {
        if ((i & 3) == 0) nq = *(const float4*)(L + lane * RS + i);
        const float ni = (i & 3) == 0 ? nq.x : (i & 3) == 1 ? nq.y : (i & 3) == 2 ? nq.z : nq.w;
        const float* __restrict__ ci = cw + i * DIM;
        const float d = ((G8(ci, xv, 0) + G8(ci, xv, 8))
                       + (G8(ci, xv, 16) + G8(ci, xv, 24)));
        xv[i] = fmaf(sw[i], ni, mw[i] + d);
    }

    // ---- out: rows -> padded LDS -> coalesced NONTEMPORAL stores ----
    // (out is never re-read; nt keeps it from evicting x/noise read lines)
#pragma unroll
    for (int c = 0; c < 8; ++c) {
        *(float4*)(L + lane * RS + c * 4) =
            make_float4(xv[c * 4 + 0], xv[c * 4 + 1], xv[c * 4 + 2], xv[c * 4 + 3]);
    }
#pragma unroll
    for (int k = 0; k < 8; ++k) {
        const int f = k * 64 + lane;
        const vfloat4 v = *(const vfloat4*)(L + (f >> 3) * RS + (f & 7) * 4);
        __builtin_nontemporal_store(v, (vfloat4*)&o4[bcur + f]);
    }
}

// One thread = one row; all global I/O wave-coalesced through a padded per-wave
// LDS chunk (no cross-wave sharing -> no barriers; DS ops are in-order within a
// wave so the chunk reuse x -> noise -> out needs no explicit waits).
__global__ __launch_bounds__(BLOCK, 4) void gibbs_sweep_kernel(
    const float* __restrict__ x,
    const float* __restrict__ noise,
    const float* __restrict__ ws,
    float* __restrict__ out)
{
    __shared__ float lds[4][64 * RS];   // 4 waves * 9216 B = 36 KB/block

    const float* __restrict__ cw = ws;          // 32x32 folded coefficients
    const float* __restrict__ sw = ws + 1024;   // sqrt(1/Pii)
    const float* __restrict__ mw = ws + 1056;   // mu

    const int wid  = threadIdx.x >> 6;
    const int lane = threadIdx.x & 63;
    const long w = (long)blockIdx.x * 4 + wid;  // global wave id
    const long b0 = w * (long)TILES * 512;      // 512 float4 per 64x32 tile

    const float4* __restrict__ x4 = (const float4*)x;
    const float4* __restrict__ n4 = (const float4*)noise;
    float4* __restrict__ o4 = (float4*)out;

    float* L = lds[wid];

    // Prologue: tile 0 loads (coalesced: lane l -> float4 k*64+l).
    float4 vx[8], vn[8];
#pragma unroll
    for (int k = 0; k < 8; ++k) vx[k] = x4[b0 + k * 64 + lane];
#pragma unroll
    for (int k = 0; k < 8; ++k) vn[k] = n4[b0 + k * 64 + lane];

    gibbs_tile<true >(L, cw, sw, mw, x4, n4, o4, b0,       b0 + 512, lane, vx, vn);
    gibbs_tile<false>(L, cw, sw, mw, x4, n4, o4, b0 + 512, 0,        lane, vx, vn);
}

extern "C" void kernel_launch(void* const* d_in, const int* in_sizes, int n_in,
                              void* d_out, int out_size, void* d_ws, size_t ws_size,
                              hipStream_t stream) {
    const float* x     = (const float*)d_in[0];  // (B, 32)
    const float* noise = (const float*)d_in[1];  // (B, 32)
    const float* prec  = (const float*)d_in[2];  // (32, 32)
    const float* mu    = (const float*)d_in[3];  // (32,)
    float* out = (float*)d_out;
    float* ws  = (float*)d_ws;                   // needs 1088 floats (4.25 KB)

    const int B = in_sizes[0] / DIM;             // 1048576
    const int grid = B / (BLOCK * TILES);        // 2048 blocks

    gibbs_setup_kernel<<<1, 256, 0, stream>>>(prec, mu, ws);
    gibbs_sweep_kernel<<<grid, BLOCK, 0, stream>>>(x, noise, ws, out);
}